// Round 18
// baseline (234.001 us; speedup 1.0000x reference)
//
#include <hip/hip_runtime.h>

#define WINDOW   512
#define NFRAMES  127
#define NSAMP    32768
#define NBATCH   512
#define NFREQ    256
#define TSAMP    8448            // 33*256 samples per 32-frame tile
#define TBYTES   33792

typedef __attribute__((ext_vector_type(8)))  short short8;   // 8 x bf16
typedef __attribute__((ext_vector_type(16))) float f32x16;   // 32x32 MFMA acc
typedef __attribute__((ext_vector_type(4)))  float f4;

// f32-LDS swizzle: XOR 16B-slot bits [4:7] with row bits [10:13].
// K-read quarter (16 lanes = 16 rows) -> 16 distinct slots: conflict-free.
#define SWZF(d) ((d) ^ ((((d) >> 10) & 15) << 4))

typedef __attribute__((address_space(1))) const void gvoid_t;
typedef __attribute__((address_space(3))) void lvoid_t;

static __device__ __forceinline__ short f2bf(float x) {
    union { float f; unsigned u; } v; v.f = x;
    unsigned r = (v.u + 0x7fffu + ((v.u >> 16) & 1u)) >> 16;
    return (short)r;
}

// 8 f32 -> 8 bf16 (RNE) via v_cvt_pk_bf16_f32 (no builtin on gfx950)
static __device__ __forceinline__ short8 cvtfrag(f4 lo, f4 hi) {
    union { unsigned u[4]; short8 s; } r;
    asm("v_cvt_pk_bf16_f32 %0, %1, %2" : "=v"(r.u[0]) : "v"(lo[0]), "v"(lo[1]));
    asm("v_cvt_pk_bf16_f32 %0, %1, %2" : "=v"(r.u[1]) : "v"(lo[2]), "v"(lo[3]));
    asm("v_cvt_pk_bf16_f32 %0, %1, %2" : "=v"(r.u[2]) : "v"(hi[0]), "v"(hi[1]));
    asm("v_cvt_pk_bf16_f32 %0, %1, %2" : "=v"(r.u[3]) : "v"(hi[2]), "v"(hi[3]));
    return r.s;
}

// lgkm-only barrier: stores and in-flight DMA cross it (T4 counted-wait idea).
static __device__ __forceinline__ void lgkm_barrier() {
    __builtin_amdgcn_sched_barrier(0);
    asm volatile("s_waitcnt lgkmcnt(0)" ::: "memory");
    __builtin_amdgcn_s_barrier();
    __builtin_amdgcn_sched_barrier(0);
}

// async-stage one 33792-B tile: per-lane pre-swizzled global src -> linear LDS
static __device__ __forceinline__ void dma_tile(const char* abase, int samp0,
                                                float* lbuf, int wid, int lane) {
    for (int r = wid; r < 33; r += 8) {
        const int d  = r * 1024 + lane * 16;           // tile-local dest byte
        int so = samp0 * 4 + SWZF(d);                  // swizzled src byte
        if (so > (NSAMP * 4 - 16)) so = NSAMP * 4 - 16;   // clamp (pad row 127)
        __builtin_amdgcn_global_load_lds((gvoid_t*)(abase + so),
                                         (lvoid_t*)((char*)lbuf + r * 1024),
                                         16, 0, 0);
    }
}

// ---- kernel 1: normalize basis -> bf16 32x32-fragment-major layout --------
// Bf[(ns*32 + ks)*64 + (n&31) + 32*kg2][8] holds B[n][k = ks*16 + kg2*8 + j]
// (real n -> ns 0..7, imag -> ns 8..15). Proven since R10.
__global__ __launch_bounds__(256) void prep_kernel(const float* __restrict__ br,
                                                   const float* __restrict__ bi,
                                                   short* __restrict__ Bf) {
    const int lane = threadIdx.x & 63;
    const int wid  = threadIdx.x >> 6;
    const int n    = blockIdx.x * 4 + wid;          // freq 0..255
    const float* pr = br + (size_t)n * WINDOW + lane * 8;
    const float* pi = bi + (size_t)n * WINDOW + lane * 8;
    f4 r0 = *(const f4*)pr;
    f4 r1 = *(const f4*)(pr + 4);
    f4 i0 = *(const f4*)pi;
    f4 i1 = *(const f4*)(pi + 4);
    float ss = 0.f;
#pragma unroll
    for (int j = 0; j < 4; ++j)
        ss += r0[j]*r0[j] + r1[j]*r1[j] + i0[j]*i0[j] + i1[j]*i1[j];
#pragma unroll
    for (int d = 1; d < 64; d <<= 1) ss += __shfl_xor(ss, d, 64);
    const float inv = 1.0f / (sqrtf(ss) + 1e-8f);
    short8 hr, hi;
#pragma unroll
    for (int j = 0; j < 4; ++j) {
        hr[j]     = f2bf(r0[j] * inv);
        hr[j + 4] = f2bf(r1[j] * inv);
        hi[j]     = f2bf(i0[j] * inv);
        hi[j + 4] = f2bf(i1[j] * inv);
    }
    const int ks  = lane >> 1, kg2 = lane & 1;
    const int nsR = n >> 5;
    const int nsI = 8 + (n >> 5);
    const int sl  = (n & 31) + 32 * kg2;
    *(short8*)(Bf + ((size_t)(nsR * 32 + ks) * 64 + sl) * 8) = hr;
    *(short8*)(Bf + ((size_t)(nsI * 32 + ks) * 64 + sl) * 8) = hi;
}

// ---- kernel 2: DMA-pipelined persistent fused GEMM -------------------------
// grid = 512 (block = 1 batch); 512 thr (8 waves, 1m x 2n per wave).
// 4 tiles of 32 frames; raw f32 audio double-buffered in LDS via
// global_load_lds (pipeline state in LDS, NOT registers); A cvt'd to bf16
// in-register under MFMA. DMA(t+1) issued before K(t), waited after K(t)
// (counted: stores not yet issued); barriers are lgkm-only so stores and
// DMA stay in flight across them.
__global__ __launch_bounds__(512, 4) void mel_kernel(const float* __restrict__ audio,
                                                     const short* __restrict__ Bf,
                                                     float* __restrict__ out) {
    __shared__ float smp[2][TSAMP];   // 2 x 33792 B raw f32, SWZF-swizzled
    __shared__ float ps[33];          // per-256-sample chunk sum of squares

    const int tid  = threadIdx.x;
    const int lane = tid & 63;
    const int wid  = tid >> 6;          // 0..7

    const int b = blockIdx.x;

    float* out_norms = out;
    float* out_real  = out + 65024;
    float* out_imag  = out + 65024 + 16646144;

    const char* abase = (const char*)(audio + (size_t)b * NSAMP);

    const int rl32 = lane & 31;
    const int kg2  = lane >> 5;

    const short* bp0 = Bf + ((size_t)(2 * wid + 0) * 32 * 64 + lane) * 8;
    const short* bp1 = Bf + ((size_t)(2 * wid + 1) * 32 * 64 + lane) * 8;

    // n mapping is wave-uniform (no epilogue divergence)
    const int n0 = (2 * wid + 0) * 32 + rl32;
    const int n1 = (2 * wid + 1) * 32 + rl32;
    float* dst0 = (n0 < NFREQ) ? out_real : out_imag;
    float* dst1 = (n1 < NFREQ) ? out_real : out_imag;
    const int kc0 = n0 & (NFREQ - 1);
    const int kc1 = n1 & (NFREQ - 1);

    const int X0 = (rl32 & 15) << 4;
    const int X1 = ((rl32 + 1) & 15) << 4;
    const int rb = rl32 * 1024 + kg2 * 32;

    // ---- prologue: DMA tile 0, wait, barrier ----
    dma_tile(abase, 0, &smp[0][0], wid, lane);
    asm volatile("s_waitcnt vmcnt(0)" ::: "memory");
    __syncthreads();

#pragma unroll 1
    for (int t = 0; t < 4; ++t) {
        const float* sb = smp[t & 1];

        // ---- ps pass: 8 threads per chunk, 33 chunks, f32 exact ----
        if (tid < 264) {
            const int c = tid >> 3, q = tid & 7;
            float ss = 0.f;
#pragma unroll
            for (int j = 0; j < 8; ++j) {
                const int d = c * 1024 + q * 128 + j * 16;
                f4 v = *(const f4*)((const char*)sb + SWZF(d));
                ss += v[0]*v[0] + v[1]*v[1] + v[2]*v[2] + v[3]*v[3];
            }
            ss += __shfl_xor(ss, 1, 64);
            ss += __shfl_xor(ss, 2, 64);
            ss += __shfl_xor(ss, 4, 64);
            if (q == 0) ps[c] = ss;
        }
        lgkm_barrier();   // ps visible; K(t-1) LDS reads of smp[(t+1)&1] done

        if (tid < 32) {
            const int fr = t * 32 + tid;
            if (fr < NFRAMES)
                out_norms[b * NFRAMES + fr] = sqrtf(ps[tid] + ps[tid + 1]);
        }

        // ---- issue DMA(t+1): flies under K(t), zero register cost ----
        if (t < 3) dma_tile(abase, (t + 1) * 8192, &smp[(t + 1) & 1][0], wid, lane);

        // ---- K-loop: 32 steps of k=16; A from f32 LDS + in-reg cvt ----
        short8 eb0 = *(const short8*)bp0;
        short8 eb1 = *(const short8*)bp1;
        short8 ob0 = *(const short8*)(bp0 + 512);
        short8 ob1 = *(const short8*)(bp1 + 512);

        f32x16 acc0 = (f32x16)0.f;
        f32x16 acc1 = (f32x16)0.f;

#pragma unroll
        for (int ks = 0; ks < 32; ++ks) {
            const int X = (ks < 16) ? X0 : X1;
            const int d = rb + ks * 64;
            f4 alo = *(const f4*)((const char*)sb + (d ^ X));
            f4 ahi = *(const f4*)((const char*)sb + ((d + 16) ^ X));
            short8 a = cvtfrag(alo, ahi);
            short8 c0, c1;
            if ((ks & 1) == 0) {
                c0 = eb0; c1 = eb1;
                if (ks < 30) {
                    eb0 = *(const short8*)(bp0 + (size_t)(ks + 2) * 512);
                    eb1 = *(const short8*)(bp1 + (size_t)(ks + 2) * 512);
                }
            } else {
                c0 = ob0; c1 = ob1;
                if (ks < 30) {
                    ob0 = *(const short8*)(bp0 + (size_t)(ks + 2) * 512);
                    ob1 = *(const short8*)(bp1 + (size_t)(ks + 2) * 512);
                }
            }
            acc0 = __builtin_amdgcn_mfma_f32_32x32x16_bf16(a, c0, acc0, 0, 0, 0);
            acc1 = __builtin_amdgcn_mfma_f32_32x32x16_bf16(a, c1, acc1, 0, 0, 0);
        }

        // DMA(t+1) landed (stores not yet issued -> this waits only the DMA)
        asm volatile("s_waitcnt vmcnt(0)" ::: "memory");
        __builtin_amdgcn_sched_barrier(0);

        // ---- epilogue: iv from ps, store (stores cross the bottom barrier) ----
#pragma unroll
        for (int r = 0; r < 16; ++r) {
            const int rr = (r & 3) + 8 * (r >> 2) + 4 * kg2;
            const int fr = t * 32 + rr;
            if (fr < NFRAMES) {
                const float iv = 1.0f / (sqrtf(ps[rr] + ps[rr + 1]) + 1e-8f);
                const size_t row = ((size_t)b * NFRAMES + fr) * NFREQ;
                dst0[row + kc0] = acc0[r] * iv;
                dst1[row + kc1] = acc1[r] * iv;
            }
        }

        lgkm_barrier();   // ps/eval done everywhere; stores stay in flight
    }
}

extern "C" void kernel_launch(void* const* d_in, const int* in_sizes, int n_in,
                              void* d_out, int out_size, void* d_ws, size_t ws_size,
                              hipStream_t stream) {
    const float* audio = (const float*)d_in[0];
    const float* br    = (const float*)d_in[1];
    const float* bi    = (const float*)d_in[2];
    float* out = (float*)d_out;
    short* Bf  = (short*)d_ws;               // 512x512 bf16 = 512 KiB

    prep_kernel<<<64, 256, 0, stream>>>(br, bi, Bf);
    mel_kernel<<<NBATCH, 512, 0, stream>>>(audio, Bf, out);
}

// Round 19
// 68.408 us; speedup vs baseline: 3.4207x; 3.4207x over previous
//
#include <hip/hip_runtime.h>

#define WINDOW   512
#define STEPSZ   256
#define NFRAMES  127
#define NSAMP    32768
#define NBATCH   512
#define NFREQ    256
#define BM       64
#define SAMP_TILE 16640          // 65 * 256 samples per tile
#define NPS      65

typedef __attribute__((ext_vector_type(8)))  short short8;   // 8 x bf16
typedef __attribute__((ext_vector_type(4)))  short bf16x4v;  // 4 x bf16
typedef __attribute__((ext_vector_type(16))) float f32x16;   // 32x32 MFMA acc
typedef __attribute__((ext_vector_type(4)))  float f4;

// Verified pattern (G4): spread row-bits (byte bits 9-11) into 16B-slot bits.
#define SWZ(byt) ((byt) ^ ((((byt) >> 9) & 7) << 4))

static __device__ __forceinline__ short f2bf(float x) {
    union { float f; unsigned u; } v; v.f = x;
    unsigned r = (v.u + 0x7fffu + ((v.u >> 16) & 1u)) >> 16;
    return (short)r;
}

// ---- kernel 1: normalize basis -> bf16 32x32-fragment-major layout --------
// Bf[(ns*32 + ks)*64 + (n&31) + 32*kg2][8] holds B[n][k = ks*16 + kg2*8 + j]
// (real n -> ns 0..7, imag -> ns 8..15). Proven since R10.
__global__ __launch_bounds__(256) void prep_kernel(const float* __restrict__ br,
                                                   const float* __restrict__ bi,
                                                   short* __restrict__ Bf) {
    const int lane = threadIdx.x & 63;
    const int wid  = threadIdx.x >> 6;
    const int n    = blockIdx.x * 4 + wid;          // freq 0..255
    const float* pr = br + (size_t)n * WINDOW + lane * 8;
    const float* pi = bi + (size_t)n * WINDOW + lane * 8;
    f4 r0 = *(const f4*)pr;
    f4 r1 = *(const f4*)(pr + 4);
    f4 i0 = *(const f4*)pi;
    f4 i1 = *(const f4*)(pi + 4);
    float ss = 0.f;
#pragma unroll
    for (int j = 0; j < 4; ++j)
        ss += r0[j]*r0[j] + r1[j]*r1[j] + i0[j]*i0[j] + i1[j]*i1[j];
#pragma unroll
    for (int d = 1; d < 64; d <<= 1) ss += __shfl_xor(ss, d, 64);
    const float inv = 1.0f / (sqrtf(ss) + 1e-8f);
    short8 hr, hi;
#pragma unroll
    for (int j = 0; j < 4; ++j) {
        hr[j]     = f2bf(r0[j] * inv);
        hr[j + 4] = f2bf(r1[j] * inv);
        hi[j]     = f2bf(i0[j] * inv);
        hi[j + 4] = f2bf(i1[j] * inv);
    }
    const int ks  = lane >> 1, kg2 = lane & 1;
    const int nsR = n >> 5;
    const int nsI = 8 + (n >> 5);
    const int sl  = (n & 31) + 32 * kg2;
    *(short8*)(Bf + ((size_t)(nsR * 32 + ks) * 64 + sl) * 8) = hr;
    *(short8*)(Bf + ((size_t)(nsI * 32 + ks) * 64 + sl) * 8) = hi;
}

// ---- kernel 2: fused norms + bf16 32x32x16 MFMA GEMM, 6 waves/SIMD ---------
// grid = 512 b * 2 m-halves * 2 n-chunks = 2048 blocks; 512 thr (8 waves).
// Wave = 2m-supers x 1n-super (acc[2][1] = 32 AGPR, ~80 regs total, proven
// correct in R16). __launch_bounds__(512,6): reg cap 85 -> 3 blocks/CU
// (LDS 3 x 33.8 KB), 24 waves/CU. 8 blocks/CU of staggered work gives the
// scheduler independent phases to overlap (stores || staging || K-loop).
__global__ __launch_bounds__(512, 6) void mel_kernel(const float* __restrict__ audio,
                                                     const short* __restrict__ Bf,
                                                     float* __restrict__ out) {
    __shared__ short smp[SAMP_TILE];   // 33280 B, swizzled bf16 samples
    __shared__ float ps[NPS + 1];
    __shared__ float invn[BM];

    const int tid  = threadIdx.x;
    const int lane = tid & 63;
    const int wid  = tid >> 6;          // 0..7

    const int b  = blockIdx.x >> 2;
    const int mh = (blockIdx.x >> 1) & 1;
    const int nc = blockIdx.x & 1;
    const int f0 = mh * BM;

    float* out_norms = out;
    float* out_real  = out + 65024;
    float* out_imag  = out + 65024 + 16646144;

    const float* abase = audio + (size_t)b * NSAMP + f0 * STEPSZ;
    const int smax = NSAMP - f0 * STEPSZ - 4;

    const int rl32 = lane & 31;
    const int kg2  = lane >> 5;
    const int ns   = nc * 8 + wid;      // n-super 0..15 (wave-uniform)

    const short* bp = Bf + ((size_t)ns * 32 * 64 + lane) * 8;

    // ---- Phase 1: stream 4 samples/thread/iter (1 live f4) + norm partials ----
#pragma unroll
    for (int it = 0; it < 9; ++it) {
        const int sl = it * 2048 + tid * 4;
        float ss = 0.f;
        if (sl < SAMP_TILE) {
            const int slc = sl < smax ? sl : smax;
            f4 v = *(const f4*)(abase + slc);
            bf16x4v h;
#pragma unroll
            for (int q = 0; q < 4; ++q) {
                ss += v[q] * v[q];
                h[q] = f2bf(v[q]);
            }
            *(bf16x4v*)((char*)smp + SWZ(sl * 2));
            *(bf16x4v*)((char*)smp + SWZ(sl * 2)) = h;
        }
        // 64 lanes span exactly one 256-sample chunk
        ss += __shfl_xor(ss, 1, 64);
        ss += __shfl_xor(ss, 2, 64);
        ss += __shfl_xor(ss, 4, 64);
        ss += __shfl_xor(ss, 8, 64);
        ss += __shfl_xor(ss, 16, 64);
        ss += __shfl_xor(ss, 32, 64);
        const int chunk = (it * 2048 + tid * 4) >> 8;
        if ((tid & 63) == 0 && chunk < NPS) ps[chunk] = ss;
    }
    __syncthreads();

    // ---- norms: frame f covers chunks f, f+1 ----
    if (tid < BM) {
        const float nrm = sqrtf(ps[tid] + ps[tid + 1]);
        const int fr = f0 + tid;
        if (fr < NFRAMES && nc == 0) out_norms[b * NFRAMES + fr] = nrm;
        invn[tid] = 1.0f / (nrm + 1e-8f);
    }
    __syncthreads();

    // ---- Phase 2: K-loop (32 steps of k=16), wave = 2 MFMA/step ----
    const int rb0 = rl32 * 512 + kg2 * 16;
    const int rb1 = (32 + rl32) * 512 + kg2 * 16;
    const int X0  = (rl32 & 7) << 4;
    const int X1  = ((rl32 + 1) & 7) << 4;
    const char* sb = (const char*)smp;

    // even/odd depth-2 B prefetch (8 VGPR)
    short8 eb = *(const short8*)bp;
    short8 ob = *(const short8*)(bp + 512);

    f32x16 acc0 = (f32x16)0.f;
    f32x16 acc1 = (f32x16)0.f;

#pragma unroll
    for (int ks = 0; ks < 32; ++ks) {
        const int X  = (ks < 16) ? X0 : X1;
        const int kb = ks * 32;
        short8 a0 = *(const short8*)(sb + ((rb0 + kb) ^ X));
        short8 a1 = *(const short8*)(sb + ((rb1 + kb) ^ X));
        short8 cb;
        if ((ks & 1) == 0) {
            cb = eb;
            if (ks < 30) eb = *(const short8*)(bp + (size_t)(ks + 2) * 512);
        } else {
            cb = ob;
            if (ks < 30) ob = *(const short8*)(bp + (size_t)(ks + 2) * 512);
        }
        acc0 = __builtin_amdgcn_mfma_f32_32x32x16_bf16(a0, cb, acc0, 0, 0, 0);
        acc1 = __builtin_amdgcn_mfma_f32_32x32x16_bf16(a1, cb, acc1, 0, 0, 0);
    }

    // ---- Epilogue: C/D map col=lane&31, row=(reg&3)+8*(reg>>2)+4*(lane>>5) ----
    const int n    = ns * 32 + rl32;                // wave-uniform real/imag
    float* dst     = (n < NFREQ) ? out_real : out_imag;
    const int kcol = n & (NFREQ - 1);
#pragma unroll
    for (int mi = 0; mi < 2; ++mi) {
        const f32x16 a = mi ? acc1 : acc0;
        const int rbase = mi * 32 + 4 * kg2;
#pragma unroll
        for (int r = 0; r < 16; ++r) {
            const int rr = rbase + (r & 3) + 8 * (r >> 2);
            const int fr = f0 + rr;
            if (fr < NFRAMES)
                dst[((size_t)b * NFRAMES + fr) * NFREQ + kcol] = a[r] * invn[rr];
        }
    }
}

extern "C" void kernel_launch(void* const* d_in, const int* in_sizes, int n_in,
                              void* d_out, int out_size, void* d_ws, size_t ws_size,
                              hipStream_t stream) {
    const float* audio = (const float*)d_in[0];
    const float* br    = (const float*)d_in[1];
    const float* bi    = (const float*)d_in[2];
    float* out = (float*)d_out;
    short* Bf  = (short*)d_ws;               // 512x512 bf16 = 512 KiB

    prep_kernel<<<64, 256, 0, stream>>>(br, bi, Bf);
    mel_kernel<<<NBATCH * 4, 512, 0, stream>>>(audio, Bf, out);
}